// Round 1
// baseline (132.970 us; speedup 1.0000x reference)
//
#include <hip/hip_runtime.h>

// HungarianMatcher cost matrix: C[n,t] = 5*L1(box_n, box_t) + 2*(pos-neg)[n, id_t] - 2*GIoU(n,t)
// bs=16, nq=900 -> N=14400 rows; T=1600 targets; nc=91 classes.
// Strategy: block = ROWS(8) rows x all T. Per-block LDS table cdiff[8][91]
// (focal class cost) + pred-box geometry; inner loop float4-vectorized over t.

#define NC 91
#define TT 1600
#define T4 (TT / 4)        // 400 float4 columns
#define ROWS 8
#define NTHREADS 256

__global__ __launch_bounds__(NTHREADS) void matcher_kernel(
    const float* __restrict__ logits,      // [N, 91]
    const float4* __restrict__ pboxes,     // [N] (cx,cy,w,h)
    const int4* __restrict__ tids,         // [T/4]
    const float4* __restrict__ tboxes,     // [T] (cx,cy,w,h)
    float4* __restrict__ out)              // [N, T/4]
{
    __shared__ float cdiff[ROWS][NC];      // pos_cost - neg_cost per (row, class)
    __shared__ float pb[ROWS][9];          // x0,y0,x1,y1,area,cx,cy,w,h

    const int n0 = blockIdx.x * ROWS;
    const int tid = threadIdx.x;

    // --- per-block precompute: focal class-cost table ---
    for (int i = tid; i < ROWS * NC; i += NTHREADS) {
        const int r = i / NC, c = i - r * NC;
        const float x = logits[(size_t)(n0 + r) * NC + c];
        const float p = __builtin_amdgcn_rcpf(1.f + __expf(-x));  // sigmoid
        const float omp = 1.f - p;
        // neg = (1-alpha) * p^2 * -log(1-p+eps); pos = alpha * (1-p)^2 * -log(p+eps)
        const float neg = 0.75f * p * p * (-__logf(omp + 1e-8f));
        const float pos = 0.25f * omp * omp * (-__logf(p + 1e-8f));
        cdiff[r][c] = pos - neg;
    }
    // --- per-block precompute: pred box geometry ---
    if (tid < ROWS) {
        const float4 b = pboxes[n0 + tid];
        pb[tid][0] = b.x - 0.5f * b.z;
        pb[tid][1] = b.y - 0.5f * b.w;
        pb[tid][2] = b.x + 0.5f * b.z;
        pb[tid][3] = b.y + 0.5f * b.w;
        pb[tid][4] = b.z * b.w;           // area = w*h
        pb[tid][5] = b.x; pb[tid][6] = b.y; pb[tid][7] = b.z; pb[tid][8] = b.w;
    }
    __syncthreads();

    for (int t4 = tid; t4 < T4; t4 += NTHREADS) {
        const int4 ids = tids[t4];
        const int idv[4] = {ids.x, ids.y, ids.z, ids.w};
        float tx0[4], ty0[4], tx1[4], ty1[4], ta[4], tcx[4], tcy[4], tw[4], th[4];
#pragma unroll
        for (int j = 0; j < 4; ++j) {
            const float4 b = tboxes[t4 * 4 + j];
            tcx[j] = b.x; tcy[j] = b.y; tw[j] = b.z; th[j] = b.w;
            tx0[j] = b.x - 0.5f * b.z;
            ty0[j] = b.y - 0.5f * b.w;
            tx1[j] = b.x + 0.5f * b.z;
            ty1[j] = b.y + 0.5f * b.w;
            ta[j] = b.z * b.w;
        }
#pragma unroll
        for (int r = 0; r < ROWS; ++r) {
            const float px0 = pb[r][0], py0 = pb[r][1], px1 = pb[r][2], py1 = pb[r][3];
            const float pa  = pb[r][4], pcx = pb[r][5], pcy = pb[r][6];
            const float pw  = pb[r][7], ph  = pb[r][8];
            float4 res;
            float* resp = (float*)&res;
#pragma unroll
            for (int j = 0; j < 4; ++j) {
                // intersection
                const float iw = fmaxf(fminf(px1, tx1[j]) - fmaxf(px0, tx0[j]), 0.f);
                const float ih = fmaxf(fminf(py1, ty1[j]) - fmaxf(py0, ty0[j]), 0.f);
                const float inter = iw * ih;
                const float uni = pa + ta[j] - inter;
                // enclosing box
                const float ew = fmaxf(fmaxf(px1, tx1[j]) - fminf(px0, tx0[j]), 0.f);
                const float eh = fmaxf(fmaxf(py1, ty1[j]) - fminf(py0, ty0[j]), 0.f);
                const float ae = ew * eh;
                // giou = iou - (ae - uni)/ae = inter/uni - 1 + uni/ae
                const float giou = inter * __builtin_amdgcn_rcpf(uni) - 1.f
                                 + uni * __builtin_amdgcn_rcpf(ae);
                const float l1 = fabsf(pcx - tcx[j]) + fabsf(pcy - tcy[j])
                               + fabsf(pw - tw[j]) + fabsf(ph - th[j]);
                resp[j] = 5.f * l1 + 2.f * cdiff[r][idv[j]] - 2.f * giou;
            }
            out[(size_t)(n0 + r) * T4 + t4] = res;
        }
    }
}

extern "C" void kernel_launch(void* const* d_in, const int* in_sizes, int n_in,
                              void* d_out, int out_size, void* d_ws, size_t ws_size,
                              hipStream_t stream) {
    const float* logits  = (const float*)d_in[0];
    const float4* pboxes = (const float4*)d_in[1];
    const int4* tids     = (const int4*)d_in[2];
    const float4* tboxes = (const float4*)d_in[3];
    float4* out = (float4*)d_out;
    const int N = in_sizes[1] / 4;  // 14400 rows
    matcher_kernel<<<N / ROWS, NTHREADS, 0, stream>>>(logits, pboxes, tids, tboxes, out);
}

// Round 3
// 126.344 us; speedup vs baseline: 1.0525x; 1.0525x over previous
//
#include <hip/hip_runtime.h>

// HungarianMatcher cost matrix: C[n,t] = 5*L1(box_n,box_t) + 2*(pos-neg)[n,id_t] - 2*GIoU(n,t)
// bs=16, nq=900 -> N=14400 rows; T=1600 targets; nc=91 classes.
// Block = 8 rows x all 400 float4-columns, 448 threads (7 waves) -> single
// column pass, 89% lane utilization. LDS table holds 2*(pos-neg)+2 so epilogue:
//   res = 5*L1 + tab[r][id] - 2*inter*rcp(uni) - 2*uni*rcp(ae)
// Nontemporal stores via native clang vector type (HIP float4 is a class and
// is rejected by __builtin_nontemporal_store).

#define NC 91
#define TT 1600
#define T4 (TT / 4)        // 400 float4 columns
#define ROWS 8
#define NTHREADS 448

typedef float vfloat4 __attribute__((ext_vector_type(4)));

__global__ __launch_bounds__(NTHREADS) void matcher_kernel(
    const float* __restrict__ logits,      // [N, 91]
    const float4* __restrict__ pboxes,     // [N] (cx,cy,w,h)
    const int4* __restrict__ tids,         // [T/4]
    const float4* __restrict__ tboxes,     // [T] (cx,cy,w,h)
    vfloat4* __restrict__ out)             // [N, T/4]
{
    __shared__ float tab[ROWS][NC];        // 2*(pos-neg) + 2 per (row, class)
    __shared__ float pb[ROWS][9];          // x0,y0,x1,y1,area,cx,cy,w,h

    const int n0 = blockIdx.x * ROWS;
    const int tid = threadIdx.x;

    // --- per-block precompute: focal class-cost table (scaled/shifted) ---
    for (int i = tid; i < ROWS * NC; i += NTHREADS) {
        const int r = i / NC, c = i - r * NC;
        const float x = logits[(size_t)(n0 + r) * NC + c];
        const float p = __builtin_amdgcn_rcpf(1.f + __expf(-x));  // sigmoid
        const float omp = 1.f - p;
        const float neg = 0.75f * p * p * (-__logf(omp + 1e-8f));
        const float pos = 0.25f * omp * omp * (-__logf(p + 1e-8f));
        tab[r][c] = 2.f * (pos - neg) + 2.f;   // fold COST_CLASS and giou's "+1"
    }
    // --- per-block precompute: pred box geometry ---
    if (tid < ROWS) {
        const float4 b = pboxes[n0 + tid];
        pb[tid][0] = b.x - 0.5f * b.z;
        pb[tid][1] = b.y - 0.5f * b.w;
        pb[tid][2] = b.x + 0.5f * b.z;
        pb[tid][3] = b.y + 0.5f * b.w;
        pb[tid][4] = b.z * b.w;           // area = w*h
        pb[tid][5] = b.x; pb[tid][6] = b.y; pb[tid][7] = b.z; pb[tid][8] = b.w;
    }
    __syncthreads();

    const int t4 = tid;
    if (t4 < T4) {
        const int4 ids = tids[t4];
        const int idv[4] = {ids.x, ids.y, ids.z, ids.w};
        float tx0[4], ty0[4], tx1[4], ty1[4], ta[4], tcx[4], tcy[4], tw[4], th[4];
#pragma unroll
        for (int j = 0; j < 4; ++j) {
            const float4 b = tboxes[t4 * 4 + j];
            tcx[j] = b.x; tcy[j] = b.y; tw[j] = b.z; th[j] = b.w;
            tx0[j] = b.x - 0.5f * b.z;
            ty0[j] = b.y - 0.5f * b.w;
            tx1[j] = b.x + 0.5f * b.z;
            ty1[j] = b.y + 0.5f * b.w;
            ta[j] = b.z * b.w;
        }
#pragma unroll
        for (int r = 0; r < ROWS; ++r) {
            const float px0 = pb[r][0], py0 = pb[r][1], px1 = pb[r][2], py1 = pb[r][3];
            const float pa  = pb[r][4], pcx = pb[r][5], pcy = pb[r][6];
            const float pw  = pb[r][7], ph  = pb[r][8];
            vfloat4 res;
#pragma unroll
            for (int j = 0; j < 4; ++j) {
                // intersection / union
                const float iw = fmaxf(fminf(px1, tx1[j]) - fmaxf(px0, tx0[j]), 0.f);
                const float ih = fmaxf(fminf(py1, ty1[j]) - fmaxf(py0, ty0[j]), 0.f);
                const float inter = iw * ih;
                const float uni = pa + ta[j] - inter;
                // enclosing box
                const float ew = fmaxf(fmaxf(px1, tx1[j]) - fminf(px0, tx0[j]), 0.f);
                const float eh = fmaxf(fmaxf(py1, ty1[j]) - fminf(py0, ty0[j]), 0.f);
                const float ae = ew * eh;
                const float l1 = fabsf(pcx - tcx[j]) + fabsf(pcy - tcy[j])
                               + fabsf(pw - tw[j]) + fabsf(ph - th[j]);
                // res = 5*L1 + [2*(pos-neg)+2] - 2*inter/uni - 2*uni/ae
                res[j] = 5.f * l1 + tab[r][idv[j]]
                       - 2.f * inter * __builtin_amdgcn_rcpf(uni)
                       - 2.f * uni * __builtin_amdgcn_rcpf(ae);
            }
            __builtin_nontemporal_store(res, &out[(size_t)(n0 + r) * T4 + t4]);
        }
    }
}

extern "C" void kernel_launch(void* const* d_in, const int* in_sizes, int n_in,
                              void* d_out, int out_size, void* d_ws, size_t ws_size,
                              hipStream_t stream) {
    const float* logits  = (const float*)d_in[0];
    const float4* pboxes = (const float4*)d_in[1];
    const int4* tids     = (const int4*)d_in[2];
    const float4* tboxes = (const float4*)d_in[3];
    vfloat4* out = (vfloat4*)d_out;
    const int N = in_sizes[1] / 4;  // 14400 rows
    matcher_kernel<<<N / ROWS, NTHREADS, 0, stream>>>(logits, pboxes, tids, tboxes, out);
}

// Round 4
// 123.780 us; speedup vs baseline: 1.0742x; 1.0207x over previous
//
#include <hip/hip_runtime.h>

// HungarianMatcher cost matrix: C[n,t] = 5*L1(box_n,box_t) + 2*(pos-neg)[n,id_t] - 2*GIoU(n,t)
// bs=16, nq=900 -> N=14400 rows; T=1600 targets; nc=91 classes.
// Block = 8 rows x 400 float4-columns, 448 threads. LDS holds only the focal
// class-cost table (2*(pos-neg)+2); pred-box geometry is read with a
// block-uniform address -> scalar loads + SALU, off the vector pipe.
// Enclosing box via min+max identity: ew = (pw+tw) - iw_raw (exact for
// well-formed boxes; reference clamp is a no-op since w,h >= 0).
// Nontemporal float4 stores; output stream is absorbed by Infinity Cache.

#define NC 91
#define TT 1600
#define T4 (TT / 4)        // 400 float4 columns
#define ROWS 8
#define NTHREADS 448

typedef float vfloat4 __attribute__((ext_vector_type(4)));

__global__ __launch_bounds__(NTHREADS) void matcher_kernel(
    const float* __restrict__ logits,      // [N, 91]
    const float4* __restrict__ pboxes,     // [N] (cx,cy,w,h)
    const int4* __restrict__ tids,         // [T/4]
    const float4* __restrict__ tboxes,     // [T] (cx,cy,w,h)
    vfloat4* __restrict__ out)             // [N, T/4]
{
    __shared__ float tab[ROWS][NC];        // 2*(pos-neg) + 2 per (row, class)

    const int n0 = blockIdx.x * ROWS;
    const int tid = threadIdx.x;

    // --- per-block precompute: focal class-cost table (scaled/shifted) ---
    for (int i = tid; i < ROWS * NC; i += NTHREADS) {
        const int r = i / NC, c = i - r * NC;
        const float x = logits[(size_t)(n0 + r) * NC + c];
        const float p = __builtin_amdgcn_rcpf(1.f + __expf(-x));  // sigmoid
        const float omp = 1.f - p;
        const float neg = 0.75f * p * p * (-__logf(omp + 1e-8f));
        const float pos = 0.25f * omp * omp * (-__logf(p + 1e-8f));
        tab[r][c] = 2.f * (pos - neg) + 2.f;   // fold COST_CLASS and giou's "+1"
    }
    __syncthreads();

    const int t4 = tid;
    if (t4 < T4) {
        const int4 ids = tids[t4];
        const int idv[4] = {ids.x, ids.y, ids.z, ids.w};
        float tx0[4], ty0[4], tx1[4], ty1[4], ta[4], tcx[4], tcy[4], tw[4], th[4];
#pragma unroll
        for (int j = 0; j < 4; ++j) {
            const float4 b = tboxes[t4 * 4 + j];
            tcx[j] = b.x; tcy[j] = b.y; tw[j] = b.z; th[j] = b.w;
            tx0[j] = b.x - 0.5f * b.z;
            ty0[j] = b.y - 0.5f * b.w;
            tx1[j] = b.x + 0.5f * b.z;
            ty1[j] = b.y + 0.5f * b.w;
            ta[j] = b.z * b.w;
        }
#pragma unroll
        for (int r = 0; r < ROWS; ++r) {
            // block-uniform address -> compiler emits s_load + scalar ALU
            const float4 b = pboxes[n0 + r];
            const float pcx = b.x, pcy = b.y, pw = b.z, ph = b.w;
            const float px0 = pcx - 0.5f * pw, py0 = pcy - 0.5f * ph;
            const float px1 = pcx + 0.5f * pw, py1 = pcy + 0.5f * ph;
            const float pa  = pw * ph;
            vfloat4 res;
#pragma unroll
            for (int j = 0; j < 4; ++j) {
                // intersection (raw, may be negative)
                const float iwr = fminf(px1, tx1[j]) - fmaxf(px0, tx0[j]);
                const float ihr = fminf(py1, ty1[j]) - fmaxf(py0, ty0[j]);
                const float inter = fmaxf(iwr, 0.f) * fmaxf(ihr, 0.f);
                const float uni = pa + ta[j] - inter;
                // enclosing box via min+max identity (clamp is a no-op: w,h>=0)
                const float ew = (pw + tw[j]) - iwr;
                const float eh = (ph + th[j]) - ihr;
                const float ae = ew * eh;
                const float l1 = fabsf(pcx - tcx[j]) + fabsf(pcy - tcy[j])
                               + fabsf(pw - tw[j]) + fabsf(ph - th[j]);
                // res = 5*L1 + [2*(pos-neg)+2] - 2*inter/uni - 2*uni/ae
                res[j] = 5.f * l1 + tab[r][idv[j]]
                       - 2.f * inter * __builtin_amdgcn_rcpf(uni)
                       - 2.f * uni * __builtin_amdgcn_rcpf(ae);
            }
            __builtin_nontemporal_store(res, &out[(size_t)(n0 + r) * T4 + t4]);
        }
    }
}

extern "C" void kernel_launch(void* const* d_in, const int* in_sizes, int n_in,
                              void* d_out, int out_size, void* d_ws, size_t ws_size,
                              hipStream_t stream) {
    const float* logits  = (const float*)d_in[0];
    const float4* pboxes = (const float4*)d_in[1];
    const int4* tids     = (const int4*)d_in[2];
    const float4* tboxes = (const float4*)d_in[3];
    vfloat4* out = (vfloat4*)d_out;
    const int N = in_sizes[1] / 4;  // 14400 rows
    matcher_kernel<<<N / ROWS, NTHREADS, 0, stream>>>(logits, pboxes, tids, tboxes, out);
}